// Round 1
// baseline (1320.849 us; speedup 1.0000x reference)
//
#include <hip/hip_runtime.h>

#define NUM_LABELS 8
#define NUM_PROTOS 64
#define B_SZ 1024
#define T_SZ 256
#define D_SZ 1024
#define M_SZ 512   // NUM_LABELS * NUM_PROTOS

// Kernel A: c[l][d] = (1/64) sum_p W[p*8+l][d]   (label-averaged prototypes, [8 x 1024])
//           s[l]    = (1/64) sum_p ||W[p*8+l]||^2
// 8 blocks (one per label), 256 threads, float4 per thread over D.
__global__ void proto_reduce(const float* __restrict__ W,
                             float* __restrict__ c,
                             float* __restrict__ s) {
    const int l   = blockIdx.x;   // 0..7
    const int tid = threadIdx.x;  // 0..255 -> float4 index over D
    float4 acc = make_float4(0.f, 0.f, 0.f, 0.f);
    float  sq  = 0.f;
    for (int p = 0; p < NUM_PROTOS; ++p) {
        const float4* row = (const float4*)(W + (size_t)(p * NUM_LABELS + l) * D_SZ);
        float4 v = row[tid];
        acc.x += v.x; acc.y += v.y; acc.z += v.z; acc.w += v.w;
        sq    += v.x * v.x + v.y * v.y + v.z * v.z + v.w * v.w;
    }
    const float inv = 1.0f / (float)NUM_PROTOS;
    float4 o = make_float4(acc.x * inv, acc.y * inv, acc.z * inv, acc.w * inv);
    ((float4*)(c + (size_t)l * D_SZ))[tid] = o;

    // block-reduce sq
    __shared__ float red[256];
    red[tid] = sq;
    __syncthreads();
    for (int off = 128; off > 0; off >>= 1) {
        if (tid < off) red[tid] += red[tid + off];
        __syncthreads();
    }
    if (tid == 0) s[l] = red[0] * inv;
}

// Kernel B: one block per batch row b.
// a[b,:] = mean_t H[b,t,:]; out[b,l] = 2*a.c[l] - ||a||^2 - s[l]
__global__ __launch_bounds__(256) void pool_dot(const float* __restrict__ H,
                                                const float* __restrict__ c,
                                                const float* __restrict__ s,
                                                float* __restrict__ out) {
    const int b   = blockIdx.x;
    const int tid = threadIdx.x;            // float4 index over D (0..255)
    const float4* Hb = (const float4*)(H + (size_t)b * T_SZ * D_SZ);
    const int rowStride = D_SZ / 4;         // 256 float4 per time-row

    float4 acc = make_float4(0.f, 0.f, 0.f, 0.f);
    #pragma unroll 8
    for (int t = 0; t < T_SZ; ++t) {
        float4 v = Hb[(size_t)t * rowStride + tid];
        acc.x += v.x; acc.y += v.y; acc.z += v.z; acc.w += v.w;
    }
    const float invT = 1.0f / (float)T_SZ;
    float4 a = make_float4(acc.x * invT, acc.y * invT, acc.z * invT, acc.w * invT);

    // 9 partial scalars per thread: [0] = ||a||^2 chunk, [1+l] = a . c[l] chunk
    float part[9];
    part[0] = a.x * a.x + a.y * a.y + a.z * a.z + a.w * a.w;
    #pragma unroll
    for (int l = 0; l < NUM_LABELS; ++l) {
        float4 cv = ((const float4*)(c + (size_t)l * D_SZ))[tid];
        part[1 + l] = a.x * cv.x + a.y * cv.y + a.z * cv.z + a.w * cv.w;
    }

    // wave(64)-level shuffle reduce, then cross-wave via LDS
    const int lane = tid & 63;
    const int wave = tid >> 6;              // 0..3
    __shared__ float red[4 * 9];
    __shared__ float fin[9];
    #pragma unroll
    for (int i = 0; i < 9; ++i) {
        float v = part[i];
        #pragma unroll
        for (int off = 32; off > 0; off >>= 1) v += __shfl_down(v, off, 64);
        if (lane == 0) red[wave * 9 + i] = v;
    }
    __syncthreads();
    if (tid < 9) {
        fin[tid] = red[0 * 9 + tid] + red[1 * 9 + tid] + red[2 * 9 + tid] + red[3 * 9 + tid];
    }
    __syncthreads();
    if (tid < NUM_LABELS) {
        out[(size_t)b * NUM_LABELS + tid] = 2.0f * fin[1 + tid] - fin[0] - s[tid];
    }
}

extern "C" void kernel_launch(void* const* d_in, const int* in_sizes, int n_in,
                              void* d_out, int out_size, void* d_ws, size_t ws_size,
                              hipStream_t stream) {
    const float* H = (const float*)d_in[0];   // [1024, 256, 1024] fp32
    const float* W = (const float*)d_in[1];   // [512, 1024] fp32
    float* out = (float*)d_out;               // [1024, 8] fp32

    float* c = (float*)d_ws;                  // [8, 1024]
    float* s = c + NUM_LABELS * D_SZ;         // [8]

    proto_reduce<<<NUM_LABELS, 256, 0, stream>>>(W, c, s);
    pool_dot<<<B_SZ, 256, 0, stream>>>(H, c, s, out);
}